// Round 1
// baseline (1106.248 us; speedup 1.0000x reference)
//
#include <hip/hip_runtime.h>
#include <hip/hip_bf16.h>
#include <math.h>

typedef __attribute__((ext_vector_type(8))) short short8;
typedef __attribute__((ext_vector_type(4))) float f32x4;
typedef unsigned int u32;

#define BT_ 384
#define N_ 716
#define C_ 256
#define H_ 8
#define D_ 32
#define MROWS (BT_ * N_)   /* 274944 */
#define SCALE_ 0.17677669529663687f  /* 32^-0.5 */
#define INVN_ (1.0f / 716.0f)

__device__ __forceinline__ void gload_lds16(const void* g, void* l) {
    __builtin_amdgcn_global_load_lds(
        (const __attribute__((address_space(1))) u32*)g,
        (__attribute__((address_space(3))) u32*)l, 16, 0, 0);
}

// ---------------------------------------------------------------------------
// Assemble bf16 weight matrices + fused qkv bias. Wqkv_b[768][256], Wo_b[256][256]
// ---------------------------------------------------------------------------
__global__ void prep_weights(const float* __restrict__ Wq, const float* __restrict__ bq,
                             const float* __restrict__ Wk, const float* __restrict__ bk,
                             const float* __restrict__ Wv, const float* __restrict__ bv,
                             const float* __restrict__ Wo,
                             __hip_bfloat16* __restrict__ wqkv, float* __restrict__ bqkv,
                             __hip_bfloat16* __restrict__ wo) {
    int idx = blockIdx.x * 256 + threadIdx.x;
    if (idx < 768 * 256) {
        int o = idx >> 8, c = idx & 255;
        const float* W = (o < 256) ? Wq : ((o < 512) ? Wk : Wv);
        int oo = o & 255;
        wqkv[idx] = __float2bfloat16(W[oo * 256 + c]);
    }
    if (idx < 256 * 256) wo[idx] = __float2bfloat16(Wo[idx]);
    if (idx < 768) bqkv[idx] = (idx < 256) ? bq[idx] : ((idx < 512) ? bk[idx - 256] : bv[idx - 512]);
}

// ---------------------------------------------------------------------------
// x fp32 -> bf16, plus per-(bt, channel) column sums for m (atomic, msum pre-zeroed)
// grid (384, 4), block 256. 716 = 4 * 179.
// ---------------------------------------------------------------------------
__global__ __launch_bounds__(256)
void convert_x(const float* __restrict__ x, __hip_bfloat16* __restrict__ xb,
               float* __restrict__ msum) {
    int bt = blockIdx.x, chunk = blockIdx.y;
    int c = threadIdx.x;
    size_t base = ((size_t)bt * N_ + (size_t)chunk * 179) * C_;
    float s = 0.0f;
    for (int r = 0; r < 179; ++r) {
        float v = x[base + (size_t)r * C_ + c];
        xb[base + (size_t)r * C_ + c] = __float2bfloat16(v);
        s += v;
    }
    atomicAdd(&msum[bt * C_ + c], s);
}

// ---------------------------------------------------------------------------
// Grouped 2-layer MLP -> per-channel 3-tap conv weights rw[bt][768]
// grid 384, block 256
// ---------------------------------------------------------------------------
__global__ __launch_bounds__(256)
void mlp_rw(const float* __restrict__ msum, const float* __restrict__ w1,
            const float* __restrict__ b1, const float* __restrict__ w2,
            const float* __restrict__ b2, float* __restrict__ rw) {
    int bt = blockIdx.x;
    int t = threadIdx.x;
    __shared__ float m_l[256];
    __shared__ float h1_l[256];
    m_l[t] = msum[bt * 256 + t] * INVN_;
    __syncthreads();
    int g = t >> 5;
    float a = b1[t];
    #pragma unroll
    for (int i = 0; i < 32; ++i) a += m_l[g * 32 + i] * w1[t * 32 + i];
    // exact GELU: x * 0.5 * (1 + erf(x/sqrt(2)))
    h1_l[t] = 0.5f * a * (1.0f + erff(a * 0.70710678118654752f));
    __syncthreads();
    for (int o = t; o < 768; o += 256) {
        int gg = o / 96;
        float s = b2[o];
        #pragma unroll
        for (int i = 0; i < 32; ++i) s += h1_l[gg * 32 + i] * w2[o * 32 + i];
        rw[bt * 768 + o] = s;
    }
}

// ---------------------------------------------------------------------------
// bf16 GEMM, B-transposed: out[m][o] = sum_k A[m][k] * Bm[o][k] + bias[o]
// K fixed = 256. 128x128 tile, BK=64, 4 waves, global_load_lds staging.
// grid (NCOLS/128, M/128), block 256.
// ---------------------------------------------------------------------------
template<int NCOLS, bool OUT_BF16>
__global__ __launch_bounds__(256)
void gemm_bt(const __hip_bfloat16* __restrict__ A, const __hip_bfloat16* __restrict__ Bm,
             const float* __restrict__ bias, void* __restrict__ outp) {
    __shared__ __align__(16) __hip_bfloat16 As[128 * 64];
    __shared__ __align__(16) __hip_bfloat16 Bs[128 * 64];
    const int tid  = threadIdx.x;
    const int lane = tid & 63;
    const int wave = tid >> 6;
    const int wr = wave >> 1, wc = wave & 1;
    const int l15 = lane & 15, lq = lane >> 4;
    const size_t rowBase = (size_t)blockIdx.y * 128;
    const int    colBase = blockIdx.x * 128;
    const int lrow = lane >> 3;       // 0..7   (row within 8-row stripe)
    const int lcol = (lane & 7) * 8;  // 0,8,..56

    f32x4 acc[4][4] = {};

    for (int ks = 0; ks < 256; ks += 64) {
        #pragma unroll
        for (int i = 0; i < 4; ++i) {
            int rb = wave * 32 + i * 8;
            gload_lds16(&A[(rowBase + rb + lrow) * 256 + ks + lcol], &As[rb * 64]);
            gload_lds16(&Bm[(size_t)(colBase + rb + lrow) * 256 + ks + lcol], &Bs[rb * 64]);
        }
        __syncthreads();
        #pragma unroll
        for (int kk = 0; kk < 64; kk += 32) {
            short8 af[4], bf[4];
            #pragma unroll
            for (int m = 0; m < 4; ++m)
                af[m] = *(const short8*)&As[(wr * 64 + m * 16 + l15) * 64 + kk + lq * 8];
            #pragma unroll
            for (int n = 0; n < 4; ++n)
                bf[n] = *(const short8*)&Bs[(wc * 64 + n * 16 + l15) * 64 + kk + lq * 8];
            #pragma unroll
            for (int m = 0; m < 4; ++m)
                #pragma unroll
                for (int n = 0; n < 4; ++n)
                    acc[m][n] = __builtin_amdgcn_mfma_f32_16x16x32_bf16(af[m], bf[n], acc[m][n], 0, 0, 0);
        }
        __syncthreads();
    }

    // epilogue: C/D layout col = lane&15, row = (lane>>4)*4 + j
    #pragma unroll
    for (int n = 0; n < 4; ++n) {
        int col = colBase + wc * 64 + n * 16 + l15;
        float bv = bias[col];
        #pragma unroll
        for (int m = 0; m < 4; ++m) {
            size_t row0 = rowBase + wr * 64 + m * 16 + lq * 4;
            #pragma unroll
            for (int j = 0; j < 4; ++j) {
                float val = acc[m][n][j] + bv;
                if (OUT_BF16)
                    ((__hip_bfloat16*)outp)[(row0 + j) * NCOLS + col] = __float2bfloat16(val);
                else
                    ((float*)outp)[(row0 + j) * NCOLS + col] = val;
            }
        }
    }
}

// ---------------------------------------------------------------------------
// Per-(bt,h): kv2[d][e] = (sum_n k[n,d] v[n,e]) * scale/N - scale*kmean[d]*vmean[e]
// and vmean[e].  grid 3072 (= bt*8+h), block 256: thread = (d0 = t>>5, e = t&31),
// covers d = d0 + 8r, r = 0..3.
// ---------------------------------------------------------------------------
__global__ __launch_bounds__(256)
void reduce_kv(const __hip_bfloat16* __restrict__ qkv, float* __restrict__ kv2,
               float* __restrict__ vmeanb) {
    int bh = blockIdx.x;
    int bt = bh >> 3, h = bh & 7;
    int t = threadIdx.x;
    int e = t & 31, d0 = t >> 5;
    __shared__ __hip_bfloat16 ks[64][32];
    __shared__ __hip_bfloat16 vs[64][32];
    float acc[4] = {0.f, 0.f, 0.f, 0.f};
    float ksum[4] = {0.f, 0.f, 0.f, 0.f};
    float vsum = 0.f;
    const size_t rowbase = (size_t)bt * N_;
    for (int n0 = 0; n0 < N_; n0 += 64) {
        int nn = (N_ - n0 < 64) ? (N_ - n0) : 64;
        for (int i = t; i < nn * 32; i += 256) {
            int r = i >> 5, cc = i & 31;
            size_t row = (rowbase + n0 + r) * 768;
            ks[r][cc] = qkv[row + 256 + h * 32 + cc];
            vs[r][cc] = qkv[row + 512 + h * 32 + cc];
        }
        __syncthreads();
        for (int n = 0; n < nn; ++n) {
            float vv = __bfloat162float(vs[n][e]);
            #pragma unroll
            for (int r = 0; r < 4; ++r) {
                float kk = __bfloat162float(ks[n][d0 + 8 * r]);
                acc[r]  += kk * vv;
                ksum[r] += kk;
            }
            vsum += vv;
        }
        __syncthreads();
    }
    __shared__ float km[32];
    __shared__ float vm[32];
    if (e == 0) {
        #pragma unroll
        for (int r = 0; r < 4; ++r) km[d0 + 8 * r] = ksum[r] * INVN_;
    }
    if (d0 == 0) vm[e] = vsum * INVN_;
    __syncthreads();
    float vme = vm[e];
    #pragma unroll
    for (int r = 0; r < 4; ++r) {
        int d = d0 + 8 * r;
        kv2[((size_t)bh * 32 + d) * 32 + e] = acc[r] * (SCALE_ * INVN_) - SCALE_ * km[d] * vme;
    }
    if (d0 == 0) vmeanb[bh * 32 + e] = vme;
}

// ---------------------------------------------------------------------------
// Z[n][c] = sum_d q[n, h*32+d] * kv2[h][d][e] + vmean[c]
//           + rw0*v[n-1][c] + rw1*v[n][c] + rw2*v[n+1][c]
// grid (384, 4), block 256 (thread = channel c). kv2 column held in registers;
// q broadcast across the head's 32 lanes via __shfl.
// ---------------------------------------------------------------------------
__global__ __launch_bounds__(256)
void fuse_z(const __hip_bfloat16* __restrict__ qkv, const float* __restrict__ kv2,
            const float* __restrict__ vmeanb, const float* __restrict__ rw,
            __hip_bfloat16* __restrict__ Z) {
    int bt = blockIdx.x, chunk = blockIdx.y;
    int c = threadIdx.x;
    int h = c >> 5, e = c & 31;
    float kvreg[32];
    #pragma unroll
    for (int d = 0; d < 32; ++d)
        kvreg[d] = kv2[(size_t)bt * 8192 + h * 1024 + d * 32 + e];
    float vm = vmeanb[bt * 256 + c];
    float r0 = rw[bt * 768 + c * 3 + 0];
    float r1 = rw[bt * 768 + c * 3 + 1];
    float r2 = rw[bt * 768 + c * 3 + 2];
    int n0 = chunk * 179;
    size_t rowbase = (size_t)bt * N_;
    int sbase = ((threadIdx.x & 63) < 32) ? 0 : 32;
    float vprev = (n0 > 0) ? __bfloat162float(qkv[(rowbase + n0 - 1) * 768 + 512 + c]) : 0.0f;
    float vcur  = __bfloat162float(qkv[(rowbase + n0) * 768 + 512 + c]);
    for (int r = 0; r < 179; ++r) {
        int gn = n0 + r;
        float vnext = (gn + 1 < N_) ? __bfloat162float(qkv[(rowbase + gn + 1) * 768 + 512 + c]) : 0.0f;
        float qv = __bfloat162float(qkv[(rowbase + gn) * 768 + c]);
        float s = vm;
        #pragma unroll
        for (int d = 0; d < 32; ++d)
            s += __shfl(qv, sbase + d, 64) * kvreg[d];
        s += r0 * vprev + r1 * vcur + r2 * vnext;
        Z[(rowbase + gn) * 256 + c] = __float2bfloat16(s);
        vprev = vcur; vcur = vnext;
    }
}

// ---------------------------------------------------------------------------
extern "C" void kernel_launch(void* const* d_in, const int* in_sizes, int n_in,
                              void* d_out, int out_size, void* d_ws, size_t ws_size,
                              hipStream_t stream) {
    (void)in_sizes; (void)n_in; (void)out_size; (void)ws_size;
    const float* x  = (const float*)d_in[0];
    const float* Wq = (const float*)d_in[1];  const float* bq = (const float*)d_in[2];
    const float* Wk = (const float*)d_in[3];  const float* bk = (const float*)d_in[4];
    const float* Wv = (const float*)d_in[5];  const float* bv = (const float*)d_in[6];
    const float* Wo = (const float*)d_in[7];  const float* bo = (const float*)d_in[8];
    const float* w1 = (const float*)d_in[9];  const float* b1 = (const float*)d_in[10];
    const float* w2 = (const float*)d_in[11]; const float* b2 = (const float*)d_in[12];
    float* out = (float*)d_out;

    char* ws = (char*)d_ws;
    size_t off = 0;
    auto take = [&](size_t bytes) -> char* {
        char* p = ws + off;
        off = (off + bytes + 255) & ~(size_t)255;
        return p;
    };

    __hip_bfloat16* qkv   = (__hip_bfloat16*)take((size_t)MROWS * 768 * 2);
    __hip_bfloat16* xb    = (__hip_bfloat16*)take((size_t)MROWS * 256 * 2);
    __hip_bfloat16* Zbuf  = xb;  // alias: xb dead after gemm_qkv, reused for Z
    __hip_bfloat16* wqkv  = (__hip_bfloat16*)take(768 * 256 * 2);
    __hip_bfloat16* wo    = (__hip_bfloat16*)take(256 * 256 * 2);
    float* bqkv   = (float*)take(768 * 4);
    float* msum   = (float*)take(384 * 256 * 4);
    float* rw     = (float*)take(384 * 768 * 4);
    float* kv2    = (float*)take((size_t)384 * 8192 * 4);
    float* vmeanb = (float*)take(384 * 256 * 4);

    hipMemsetAsync(msum, 0, 384 * 256 * 4, stream);

    prep_weights<<<768, 256, 0, stream>>>(Wq, bq, Wk, bk, Wv, bv, Wo, wqkv, bqkv, wo);
    convert_x<<<dim3(384, 4), 256, 0, stream>>>(x, xb, msum);
    mlp_rw<<<384, 256, 0, stream>>>(msum, w1, b1, w2, b2, rw);
    // QKV projection: [274944,256] x [768,256]^T -> bf16 qkv, bias fused
    gemm_bt<768, true><<<dim3(6, 2148), 256, 0, stream>>>(xb, wqkv, bqkv, qkv);
    reduce_kv<<<3072, 256, 0, stream>>>(qkv, kv2, vmeanb);
    fuse_z<<<dim3(384, 4), 256, 0, stream>>>(qkv, kv2, vmeanb, rw, Zbuf);
    // Output projection: [274944,256] x [256,256]^T -> f32 out, bias fused
    gemm_bt<256, false><<<dim3(2, 2148), 256, 0, stream>>>(Zbuf, wo, bo, out);
}

// Round 2
// 908.448 us; speedup vs baseline: 1.2177x; 1.2177x over previous
//
#include <hip/hip_runtime.h>
#include <hip/hip_bf16.h>
#include <math.h>

typedef __attribute__((ext_vector_type(8))) short short8;
typedef __attribute__((ext_vector_type(4))) float f32x4;
typedef unsigned int u32;

#define BT_ 384
#define N_ 716
#define C_ 256
#define H_ 8
#define D_ 32
#define MROWS (BT_ * N_)   /* 274944 */
#define SCALE_ 0.17677669529663687f  /* 32^-0.5 */
#define INVN_ (1.0f / 716.0f)

__device__ __forceinline__ void gload_lds16(const void* g, void* l) {
    __builtin_amdgcn_global_load_lds(
        (const __attribute__((address_space(1))) u32*)g,
        (__attribute__((address_space(3))) u32*)l, 16, 0, 0);
}

// ---------------------------------------------------------------------------
// Assemble bf16 weight matrices + fused qkv bias. Wqkv_b[768][256], Wo_b[256][256]
// ---------------------------------------------------------------------------
__global__ void prep_weights(const float* __restrict__ Wq, const float* __restrict__ bq,
                             const float* __restrict__ Wk, const float* __restrict__ bk,
                             const float* __restrict__ Wv, const float* __restrict__ bv,
                             const float* __restrict__ Wo,
                             __hip_bfloat16* __restrict__ wqkv, float* __restrict__ bqkv,
                             __hip_bfloat16* __restrict__ wo) {
    int idx = blockIdx.x * 256 + threadIdx.x;
    if (idx < 768 * 256) {
        int o = idx >> 8, c = idx & 255;
        const float* W = (o < 256) ? Wq : ((o < 512) ? Wk : Wv);
        int oo = o & 255;
        wqkv[idx] = __float2bfloat16(W[oo * 256 + c]);
    }
    if (idx < 256 * 256) wo[idx] = __float2bfloat16(Wo[idx]);
    if (idx < 768) bqkv[idx] = (idx < 256) ? bq[idx] : ((idx < 512) ? bk[idx - 256] : bv[idx - 512]);
}

// ---------------------------------------------------------------------------
// x fp32 -> bf16, plus per-(bt, channel) column sums for m (atomic, msum pre-zeroed)
// grid (384, 4), block 256. 716 = 4 * 179.
// ---------------------------------------------------------------------------
__global__ __launch_bounds__(256)
void convert_x(const float* __restrict__ x, __hip_bfloat16* __restrict__ xb,
               float* __restrict__ msum) {
    int bt = blockIdx.x, chunk = blockIdx.y;
    int c = threadIdx.x;
    size_t base = ((size_t)bt * N_ + (size_t)chunk * 179) * C_;
    float s = 0.0f;
    for (int r = 0; r < 179; ++r) {
        float v = x[base + (size_t)r * C_ + c];
        xb[base + (size_t)r * C_ + c] = __float2bfloat16(v);
        s += v;
    }
    atomicAdd(&msum[bt * C_ + c], s);
}

// ---------------------------------------------------------------------------
// Grouped 2-layer MLP -> per-channel 3-tap conv weights rw[bt][768]
// grid 384, block 256
// ---------------------------------------------------------------------------
__global__ __launch_bounds__(256)
void mlp_rw(const float* __restrict__ msum, const float* __restrict__ w1,
            const float* __restrict__ b1, const float* __restrict__ w2,
            const float* __restrict__ b2, float* __restrict__ rw) {
    int bt = blockIdx.x;
    int t = threadIdx.x;
    __shared__ float m_l[256];
    __shared__ float h1_l[256];
    m_l[t] = msum[bt * 256 + t] * INVN_;
    __syncthreads();
    int g = t >> 5;
    float a = b1[t];
    #pragma unroll
    for (int i = 0; i < 32; ++i) a += m_l[g * 32 + i] * w1[t * 32 + i];
    // exact GELU: x * 0.5 * (1 + erf(x/sqrt(2)))
    h1_l[t] = 0.5f * a * (1.0f + erff(a * 0.70710678118654752f));
    __syncthreads();
    for (int o = t; o < 768; o += 256) {
        int gg = o / 96;
        float s = b2[o];
        #pragma unroll
        for (int i = 0; i < 32; ++i) s += h1_l[gg * 32 + i] * w2[o * 32 + i];
        rw[bt * 768 + o] = s;
    }
}

// ---------------------------------------------------------------------------
// bf16 GEMM, B-transposed: out[m][o] = sum_k A[m][k] * Bm[o][k] + bias[o]
// K fixed = 256. 128x128 tile, BK=64, 4 waves, global_load_lds staging.
// grid (NCOLS/128, M/128), block 256.
// ---------------------------------------------------------------------------
template<int NCOLS, bool OUT_BF16>
__global__ __launch_bounds__(256)
void gemm_bt(const __hip_bfloat16* __restrict__ A, const __hip_bfloat16* __restrict__ Bm,
             const float* __restrict__ bias, void* __restrict__ outp) {
    __shared__ __align__(16) __hip_bfloat16 As[128 * 64];
    __shared__ __align__(16) __hip_bfloat16 Bs[128 * 64];
    const int tid  = threadIdx.x;
    const int lane = tid & 63;
    const int wave = tid >> 6;
    const int wr = wave >> 1, wc = wave & 1;
    const int l15 = lane & 15, lq = lane >> 4;
    const size_t rowBase = (size_t)blockIdx.y * 128;
    const int    colBase = blockIdx.x * 128;
    const int lrow = lane >> 3;       // 0..7   (row within 8-row stripe)
    const int lcol = (lane & 7) * 8;  // 0,8,..56

    f32x4 acc[4][4] = {};

    for (int ks = 0; ks < 256; ks += 64) {
        #pragma unroll
        for (int i = 0; i < 4; ++i) {
            int rb = wave * 32 + i * 8;
            gload_lds16(&A[(rowBase + rb + lrow) * 256 + ks + lcol], &As[rb * 64]);
            gload_lds16(&Bm[(size_t)(colBase + rb + lrow) * 256 + ks + lcol], &Bs[rb * 64]);
        }
        __syncthreads();
        #pragma unroll
        for (int kk = 0; kk < 64; kk += 32) {
            short8 af[4], bf[4];
            #pragma unroll
            for (int m = 0; m < 4; ++m)
                af[m] = *(const short8*)&As[(wr * 64 + m * 16 + l15) * 64 + kk + lq * 8];
            #pragma unroll
            for (int n = 0; n < 4; ++n)
                bf[n] = *(const short8*)&Bs[(wc * 64 + n * 16 + l15) * 64 + kk + lq * 8];
            #pragma unroll
            for (int m = 0; m < 4; ++m)
                #pragma unroll
                for (int n = 0; n < 4; ++n)
                    acc[m][n] = __builtin_amdgcn_mfma_f32_16x16x32_bf16(af[m], bf[n], acc[m][n], 0, 0, 0);
        }
        __syncthreads();
    }

    // epilogue: C/D layout col = lane&15, row = (lane>>4)*4 + j
    #pragma unroll
    for (int n = 0; n < 4; ++n) {
        int col = colBase + wc * 64 + n * 16 + l15;
        float bv = bias[col];
        #pragma unroll
        for (int m = 0; m < 4; ++m) {
            size_t row0 = rowBase + wr * 64 + m * 16 + lq * 4;
            #pragma unroll
            for (int j = 0; j < 4; ++j) {
                float val = acc[m][n][j] + bv;
                if (OUT_BF16)
                    ((__hip_bfloat16*)outp)[(row0 + j) * NCOLS + col] = __float2bfloat16(val);
                else
                    ((float*)outp)[(row0 + j) * NCOLS + col] = val;
            }
        }
    }
}

// ---------------------------------------------------------------------------
// Per-(bt,h): kv2[d][e] = (sum_n k[n,d] v[n,e]) * scale/N - scale*kmean[d]*vmean[e]
// Output TRANSPOSED as bf16: kv2t[bh][e][d]  (B^T fragment layout for MFMA)
// grid 3072 (= bt*8+h), block 256: thread = (d0 = t>>5, e = t&31),
// covers d = d0 + 8r, r = 0..3.
// ---------------------------------------------------------------------------
__global__ __launch_bounds__(256)
void reduce_kv(const __hip_bfloat16* __restrict__ qkv, __hip_bfloat16* __restrict__ kv2t,
               float* __restrict__ vmeanb) {
    int bh = blockIdx.x;
    int bt = bh >> 3, h = bh & 7;
    int t = threadIdx.x;
    int e = t & 31, d0 = t >> 5;
    __shared__ __hip_bfloat16 ks[64][32];
    __shared__ __hip_bfloat16 vs[64][32];
    float acc[4] = {0.f, 0.f, 0.f, 0.f};
    float ksum[4] = {0.f, 0.f, 0.f, 0.f};
    float vsum = 0.f;
    const size_t rowbase = (size_t)bt * N_;
    for (int n0 = 0; n0 < N_; n0 += 64) {
        int nn = (N_ - n0 < 64) ? (N_ - n0) : 64;
        for (int i = t; i < nn * 32; i += 256) {
            int r = i >> 5, cc = i & 31;
            size_t row = (rowbase + n0 + r) * 768;
            ks[r][cc] = qkv[row + 256 + h * 32 + cc];
            vs[r][cc] = qkv[row + 512 + h * 32 + cc];
        }
        __syncthreads();
        for (int n = 0; n < nn; ++n) {
            float vv = __bfloat162float(vs[n][e]);
            #pragma unroll
            for (int r = 0; r < 4; ++r) {
                float kk = __bfloat162float(ks[n][d0 + 8 * r]);
                acc[r]  += kk * vv;
                ksum[r] += kk;
            }
            vsum += vv;
        }
        __syncthreads();
    }
    __shared__ float km[32];
    __shared__ float vm[32];
    if (e == 0) {
        #pragma unroll
        for (int r = 0; r < 4; ++r) km[d0 + 8 * r] = ksum[r] * INVN_;
    }
    if (d0 == 0) vm[e] = vsum * INVN_;
    __syncthreads();
    float vme = vm[e];
    #pragma unroll
    for (int r = 0; r < 4; ++r) {
        int d = d0 + 8 * r;
        float val = acc[r] * (SCALE_ * INVN_) - SCALE_ * km[d] * vme;
        kv2t[((size_t)bh * 32 + e) * 32 + d] = __float2bfloat16(val);
    }
    if (d0 == 0) vmeanb[bh * 32 + e] = vme;
}

// ---------------------------------------------------------------------------
// fuse_z2: per (bt, 64-row chunk):
//   phase 1 (MFMA): attn[64][256] = q @ kv2t^T + vmean  -> LDS (bf16)
//   phase 2: Z[n][c] = attn[n][c] + rw0*v[n-1][c] + rw1*v[n][c] + rw2*v[n+1][c]
// grid (384, 12), block 256 (4 waves). LDS = 32KB attn + 16KB kv2t = 48KB.
// ---------------------------------------------------------------------------
__global__ __launch_bounds__(256)
void fuse_z2(const __hip_bfloat16* __restrict__ qkv, const __hip_bfloat16* __restrict__ kv2t,
             const float* __restrict__ vmeanb, const float* __restrict__ rw,
             __hip_bfloat16* __restrict__ Z) {
    __shared__ __align__(16) __hip_bfloat16 attn[64][256];
    __shared__ __align__(16) __hip_bfloat16 kvl[8192];   // kv2t slice for this bt
    int bt = blockIdx.x;
    int n0 = blockIdx.y * 64;
    int rows = (N_ - n0 < 64) ? (N_ - n0) : 64;          // 64 or 12
    int t = threadIdx.x;
    const size_t rowbase = (size_t)bt * N_;

    // stage kv2t[bt] (16KB) into LDS, vectorized
    {
        const __hip_bfloat16* src = kv2t + (size_t)bt * 8192;
        #pragma unroll
        for (int i = 0; i < 4; ++i) {
            int off = (t + i * 256) * 8;
            *(short8*)&kvl[off] = *(const short8*)&src[off];
        }
    }
    __syncthreads();

    // ---- phase 1: MFMA q @ kv2t -> attn (bf16, + vmean) ----
    {
        int lane = t & 63, wave = t >> 6;
        int l15 = lane & 15, lq = lane >> 4;
        int r0 = wave * 16;                               // wave's row tile
        int gn = n0 + r0 + l15; if (gn > N_ - 1) gn = N_ - 1;   // clamp (tail chunk)
        const __hip_bfloat16* qrow = qkv + (rowbase + gn) * 768;
        #pragma unroll
        for (int h = 0; h < 8; ++h) {
            short8 af = *(const short8*)&qrow[h * 32 + lq * 8];
            #pragma unroll
            for (int half = 0; half < 2; ++half) {
                short8 bf = *(const short8*)&kvl[h * 1024 + (half * 16 + l15) * 32 + lq * 8];
                f32x4 acc = {};
                acc = __builtin_amdgcn_mfma_f32_16x16x32_bf16(af, bf, acc, 0, 0, 0);
                int col = h * 32 + half * 16 + l15;
                float vm = vmeanb[bt * 256 + col];
                #pragma unroll
                for (int j = 0; j < 4; ++j)
                    attn[r0 + lq * 4 + j][col] = __float2bfloat16(acc[j] + vm);
            }
        }
    }
    __syncthreads();

    // ---- phase 2: 3-tap depthwise conv over node axis + attn, thread = channel ----
    {
        int c = t;
        float r0w = rw[bt * 768 + c * 3 + 0];
        float r1w = rw[bt * 768 + c * 3 + 1];
        float r2w = rw[bt * 768 + c * 3 + 2];
        const __hip_bfloat16* vb = qkv + rowbase * 768 + 512 + c;
        float vprev = (n0 > 0) ? __bfloat162float(vb[(size_t)(n0 - 1) * 768]) : 0.0f;
        float vcur  = __bfloat162float(vb[(size_t)n0 * 768]);
        #pragma unroll 4
        for (int r = 0; r < rows; ++r) {
            int gn = n0 + r;
            float vnext = (gn + 1 < N_) ? __bfloat162float(vb[(size_t)(gn + 1) * 768]) : 0.0f;
            float s = __bfloat162float(attn[r][c]) + r0w * vprev + r1w * vcur + r2w * vnext;
            Z[(rowbase + gn) * 256 + c] = __float2bfloat16(s);
            vprev = vcur; vcur = vnext;
        }
    }
}

// ---------------------------------------------------------------------------
extern "C" void kernel_launch(void* const* d_in, const int* in_sizes, int n_in,
                              void* d_out, int out_size, void* d_ws, size_t ws_size,
                              hipStream_t stream) {
    (void)in_sizes; (void)n_in; (void)out_size; (void)ws_size;
    const float* x  = (const float*)d_in[0];
    const float* Wq = (const float*)d_in[1];  const float* bq = (const float*)d_in[2];
    const float* Wk = (const float*)d_in[3];  const float* bk = (const float*)d_in[4];
    const float* Wv = (const float*)d_in[5];  const float* bv = (const float*)d_in[6];
    const float* Wo = (const float*)d_in[7];  const float* bo = (const float*)d_in[8];
    const float* w1 = (const float*)d_in[9];  const float* b1 = (const float*)d_in[10];
    const float* w2 = (const float*)d_in[11]; const float* b2 = (const float*)d_in[12];
    float* out = (float*)d_out;

    char* ws = (char*)d_ws;
    size_t off = 0;
    auto take = [&](size_t bytes) -> char* {
        char* p = ws + off;
        off = (off + bytes + 255) & ~(size_t)255;
        return p;
    };

    __hip_bfloat16* qkv   = (__hip_bfloat16*)take((size_t)MROWS * 768 * 2);
    __hip_bfloat16* xb    = (__hip_bfloat16*)take((size_t)MROWS * 256 * 2);
    __hip_bfloat16* Zbuf  = xb;  // alias: xb dead after gemm_qkv, reused for Z
    __hip_bfloat16* wqkv  = (__hip_bfloat16*)take(768 * 256 * 2);
    __hip_bfloat16* wo    = (__hip_bfloat16*)take(256 * 256 * 2);
    float* bqkv   = (float*)take(768 * 4);
    float* msum   = (float*)take(384 * 256 * 4);
    float* rw     = (float*)take(384 * 768 * 4);
    __hip_bfloat16* kv2t = (__hip_bfloat16*)take((size_t)384 * 8192 * 2);
    float* vmeanb = (float*)take(384 * 256 * 4);

    hipMemsetAsync(msum, 0, 384 * 256 * 4, stream);

    prep_weights<<<768, 256, 0, stream>>>(Wq, bq, Wk, bk, Wv, bv, Wo, wqkv, bqkv, wo);
    convert_x<<<dim3(384, 4), 256, 0, stream>>>(x, xb, msum);
    mlp_rw<<<384, 256, 0, stream>>>(msum, w1, b1, w2, b2, rw);
    // QKV projection: [274944,256] x [768,256]^T -> bf16 qkv, bias fused
    gemm_bt<768, true><<<dim3(6, 2148), 256, 0, stream>>>(xb, wqkv, bqkv, qkv);
    reduce_kv<<<3072, 256, 0, stream>>>(qkv, kv2t, vmeanb);
    fuse_z2<<<dim3(384, 12), 256, 0, stream>>>(qkv, kv2t, vmeanb, rw, Zbuf);
    // Output projection: [274944,256] x [256,256]^T -> f32 out, bias fused
    gemm_bt<256, false><<<dim3(2, 2148), 256, 0, stream>>>(Zbuf, wo, bo, out);
}